// Round 14
// baseline (1636.926 us; speedup 1.0000x reference)
//
#include <hip/hip_runtime.h>
#include <hip/hip_bf16.h>
#include <hip/hip_cooperative_groups.h>

namespace cg = cooperative_groups;

#define NN 10000
#define NE 100000
#define NTILES ((NE + 63) / 64)

typedef __bf16 bf16x8 __attribute__((ext_vector_type(8)));
typedef float  f32x4  __attribute__((ext_vector_type(4)));

__device__ __forceinline__ f32x4 relu4(f32x4 a) {
    a.x = fmaxf(a.x, 0.f); a.y = fmaxf(a.y, 0.f);
    a.z = fmaxf(a.z, 0.f); a.w = fmaxf(a.w, 0.f);
    return a;
}

struct MegaArgs {
    const float *x, *eattr, *cinit, *fc1w, *fc1b;
    const float *kw1, *kb1, *kw2, *kb2, *kw3, *kb3;
    const float *cmw1, *cmb1, *cmw2, *f2w1, *f2b1, *f2w2, *f2b2;
    const int* eidx;
    float *h, *coord, *deg_inv, *cds, *m_s, *phis, *out;
    int *deg, *rowptr, *cursor, *pos_r, *tctr;
    __bf16 *w3sw, *w2sw;
};

// The entire pipeline in one cooperative kernel. Phases separated by grid
// sync; layer tiles dynamically scheduled via a global atomic counter.
__global__ __launch_bounds__(256, 2) void k_mega(MegaArgs a) {
    cg::grid_group gg = cg::this_grid();
    __shared__ float smem[4 * 64 * 36];            // 36.9 KB (kt1/kt2/wk/mvx overlay)
    __shared__ int s_tile;
    __shared__ int ssum[256];
    __bf16* kt1 = (__bf16*)smem;                   // 64 x 72 bf16
    __bf16* kt2 = (__bf16*)smem + 4608;            // 64 x 128 bf16
    const int tid  = threadIdx.x;
    const int lane = tid & 63;
    const int wave = tid >> 6;
    const int q = lane >> 4, t = lane & 15;
    const int NB = gridDim.x;
    const int gtid0 = blockIdx.x * 256 + tid;
    const int gstride = NB * 256;

    // ---- phase 0: w3/w2 swizzle + h/coord init + deg zero ----
    for (int tt = gtid0; tt < 139264 + 2 * NN; tt += gstride) {
        if (tt < 131072) {
            int jj = tt & 7, L = (tt >> 3) & 63, ks = (tt >> 9) & 3,
                jt = (tt >> 11) & 1, i = tt >> 12;
            int c    = ks*32 + (L >> 4)*8 + jj;
            int colv = i*32 + jt*16 + (L & 15);
            a.w3sw[tt] = (__bf16)a.kw3[c*1024 + colv];
        } else if (tt < 139264) {
            int u = tt - 131072;
            int jj = u & 7, L = (u >> 3) & 63, ks = (u >> 9) & 1, nt = u >> 10;
            int c1 = ks*32 + (L >> 4)*8 + jj;
            int c2 = nt*16 + (L & 15);
            a.w2sw[u] = (__bf16)a.kw2[c1*128 + c2];
        } else if (tt < 139264 + NN) {
            int n = tt - 139264;
            float x0 = a.x[n*3+0], x1 = a.x[n*3+1], x2 = a.x[n*3+2];
            #pragma unroll
            for (int j = 0; j < 32; j += 4) {
                f32x4 v = *(const f32x4*)(a.fc1b + j);
                v += x0 * (*(const f32x4*)(a.fc1w + 0*32 + j));
                v += x1 * (*(const f32x4*)(a.fc1w + 1*32 + j));
                v += x2 * (*(const f32x4*)(a.fc1w + 2*32 + j));
                *(f32x4*)(a.h + (size_t)n*32 + j) = v;   // no relu (matches ref)
            }
            a.coord[n*3+0] = a.cinit[n*3+0];
            a.coord[n*3+1] = a.cinit[n*3+1];
            a.coord[n*3+2] = a.cinit[n*3+2];
        } else {
            a.deg[tt - 139264 - NN] = 0;
        }
    }
    gg.sync();

    // ---- phase 1: degree ----
    for (int e = gtid0; e < NE; e += gstride)
        atomicAdd(&a.deg[a.eidx[e]], 1);
    gg.sync();

    // ---- phase 2: exclusive scan + deg_inv (block 0) ----
    if (blockIdx.x == 0) {
        const int CH = 40;
        const int base = tid * CH;
        int s = 0;
        for (int i = 0; i < CH; ++i) { int n = base + i; if (n < NN) s += a.deg[n]; }
        ssum[tid] = s;
        __syncthreads();
        for (int off = 1; off < 256; off <<= 1) {
            int tv = (tid >= off) ? ssum[tid - off] : 0;
            __syncthreads();
            ssum[tid] += tv;
            __syncthreads();
        }
        int run = ssum[tid] - s;
        for (int i = 0; i < CH; ++i) {
            int n = base + i;
            if (n < NN) {
                int d = a.deg[n];
                a.rowptr[n] = run; a.cursor[n] = run; run += d;
                a.deg_inv[n] = 1.0f / (float)(d > 1 ? d : 1);
            }
        }
        if (tid == 255) a.rowptr[NN] = ssum[255];
    }
    gg.sync();

    // ---- phase 3: pos_r fill + tile-counter init ----
    if (gtid0 == 0) *a.tctr = 0;
    for (int e = gtid0; e < NE; e += gstride)
        a.pos_r[e] = atomicAdd(&a.cursor[a.eidx[e]], 1);
    gg.sync();

    // ---- 3 layers ----
    for (int d = 0; d < 3; ++d) {
        // ======== layer phase: dynamic tile scheduling ========
        for (;;) {
            __syncthreads();                       // prior tile's smem reads done
            if (tid == 0) s_tile = atomicAdd(a.tctr, 1);
            __syncthreads();
            const int tile = s_tile;
            if (tile >= NTILES) break;
            const int base = tile * 64;

            const int eg = base + lane;
            const int egc = eg < NE ? eg : NE - 1;
            const bool wvalid = eg < NE;
            const int pos = a.pos_r[egc];

            // early: h[col] + first B-frags (latency hidden by phases 1-2)
            int col = a.eidx[NE + egc];
            float hcol[32];
            {
                const f32x4* hp = (const f32x4*)(a.h + (size_t)col * 32);
                #pragma unroll
                for (int v = 0; v < 8; ++v) {
                    f32x4 hv = hp[v];
                    hcol[v*4+0] = hv.x; hcol[v*4+1] = hv.y;
                    hcol[v*4+2] = hv.z; hcol[v*4+3] = hv.w;
                }
            }
            bf16x8 bcur[8];
            {
                const __bf16* wb0 = a.w3sw + (size_t)(wave * 8) * 4096;
                #pragma unroll
                for (int f = 0; f < 8; ++f)
                    bcur[f] = *(const bf16x8*)(wb0 + (f*64 + lane) * 8);
            }

            // phase L1: kernel-MLP layer 1 (wave-split channels)
            {
                int r = a.eidx[egc];
                float dx = a.coord[r*3+0] - a.coord[col*3+0];
                float dy = a.coord[r*3+1] - a.coord[col*3+1];
                float dz = a.coord[r*3+2] - a.coord[col*3+2];
                float rad = dx*dx + dy*dy + dz*dz;
                if (wave == 0 && wvalid) {
                    f32x4 cdv = {dx, dy, dz, rad};
                    *(f32x4*)(a.cds + (size_t)pos*4) = cdv;
                }
                float kin[7];
                #pragma unroll
                for (int aa = 0; aa < 6; ++aa) kin[aa] = a.eattr[(size_t)egc*6 + aa];
                kin[6] = rad;

                const int g0 = wave * 16;
                f32x4 acc1[4];
                #pragma unroll
                for (int g = 0; g < 4; ++g) acc1[g] = *(const f32x4*)(a.kb1 + g0 + g*4);
                #pragma unroll
                for (int t7 = 0; t7 < 7; ++t7) {
                    float kv = kin[t7];
                    #pragma unroll
                    for (int g = 0; g < 4; ++g)
                        acc1[g] += kv * (*(const f32x4*)(a.kw1 + t7*64 + g0 + g*4));
                }
                #pragma unroll
                for (int cc = 0; cc < 2; ++cc) {
                    f32x4 a0 = relu4(acc1[cc*2]), a1 = relu4(acc1[cc*2+1]);
                    bf16x8 pk = {(__bf16)a0.x, (__bf16)a0.y, (__bf16)a0.z, (__bf16)a0.w,
                                 (__bf16)a1.x, (__bf16)a1.y, (__bf16)a1.z, (__bf16)a1.w};
                    int chunk = wave*2 + cc;
                    *(bf16x8*)(kt1 + lane*72 + ((chunk ^ (lane & 7)) * 8)) = pk;
                }
            }
            __syncthreads();                       // k1 complete

            // phase L2: layer-2 MFMA (wave handles nt = 2*wave, 2*wave+1)
            {
                bf16x8 af[4][2];
                #pragma unroll
                for (int mt = 0; mt < 4; ++mt) {
                    int ep = mt*16 + t;
                    #pragma unroll
                    for (int ks = 0; ks < 2; ++ks)
                        af[mt][ks] = *(const bf16x8*)(kt1 + ep*72 + (((ks*4 + q) ^ (ep & 7)) * 8));
                }
                #pragma unroll
                for (int nn = 0; nn < 2; ++nn) {
                    int nt = wave*2 + nn;
                    f32x4 a2[4];
                    #pragma unroll
                    for (int mt = 0; mt < 4; ++mt) a2[mt] = (f32x4){0.f, 0.f, 0.f, 0.f};
                    #pragma unroll
                    for (int ks = 0; ks < 2; ++ks) {
                        bf16x8 bf_ = *(const bf16x8*)(a.w2sw + ((nt*2 + ks)*64 + lane) * 8);
                        #pragma unroll
                        for (int mt = 0; mt < 4; ++mt)
                            a2[mt] = __builtin_amdgcn_mfma_f32_16x16x32_bf16(af[mt][ks], bf_, a2[mt], 0, 0, 0);
                    }
                    float bias = a.kb2[nt*16 + t];
                    int chunk = nt*2 + (t >> 3);
                    int tin = t & 7;
                    #pragma unroll
                    for (int mt = 0; mt < 4; ++mt) {
                        #pragma unroll
                        for (int rr = 0; rr < 4; ++rr) {
                            int row = mt*16 + q*4 + rr;
                            kt2[row*128 + ((chunk ^ (row & 15)) * 8) + tin] =
                                (__bf16)fmaxf(a2[mt][rr] + bias, 0.f);
                        }
                    }
                }
            }
            __syncthreads();                       // k2 complete

            bf16x8 afrag[4][4];
            #pragma unroll
            for (int mt = 0; mt < 4; ++mt) {
                int ep = mt*16 + t;
                #pragma unroll
                for (int ks = 0; ks < 4; ++ks) {
                    int ck = ks*4 + q;
                    afrag[mt][ks] = *(const bf16x8*)(kt2 + ep*128 + ((ck ^ (ep & 15)) * 8));
                }
            }
            __syncthreads();                       // afrag loaded; wk may clobber

            // phase L3: big GEMM i-loop
            float* wkw = smem + wave * (64 * 36);
            const float* wkrow = wkw + lane * 36;
            float mv[8];

            #pragma unroll
            for (int ii = 0; ii < 8; ++ii) {
                const int i = wave * 8 + ii;
                f32x4 acc[4][2];
                #pragma unroll
                for (int mt = 0; mt < 4; ++mt) {
                    acc[mt][0] = (f32x4){0.f, 0.f, 0.f, 0.f};
                    acc[mt][1] = (f32x4){0.f, 0.f, 0.f, 0.f};
                }
                #pragma unroll
                for (int jt = 0; jt < 2; ++jt) {
                    #pragma unroll
                    for (int ks = 0; ks < 4; ++ks) {
                        bf16x8 bfrag = bcur[jt*4 + ks];
                        #pragma unroll
                        for (int mt = 0; mt < 4; ++mt)
                            acc[mt][jt] = __builtin_amdgcn_mfma_f32_16x16x32_bf16(
                                afrag[mt][ks], bfrag, acc[mt][jt], 0, 0, 0);
                    }
                }
                if (ii < 7) {
                    const __bf16* wbn = a.w3sw + (size_t)(i + 1) * 4096;
                    #pragma unroll
                    for (int f = 0; f < 8; ++f)
                        bcur[f] = *(const bf16x8*)(wbn + (f*64 + lane) * 8);
                }
                float bias0 = a.kb3[i*32 + t];
                float bias1 = a.kb3[i*32 + 16 + t];
                #pragma unroll
                for (int mt = 0; mt < 4; ++mt) {
                    #pragma unroll
                    for (int r = 0; r < 4; ++r) {
                        int row = mt*16 + q*4 + r;
                        wkw[row*36 + t]      = acc[mt][0][r] + bias0;
                        wkw[row*36 + 16 + t] = acc[mt][1][r] + bias1;
                    }
                }
                float s = 0.f;
                #pragma unroll
                for (int v = 0; v < 8; ++v) {
                    f32x4 wv = *(const f32x4*)(wkrow + v*4);
                    s += wv.x*hcol[v*4+0] + wv.y*hcol[v*4+1] + wv.z*hcol[v*4+2] + wv.w*hcol[v*4+3];
                }
                mv[ii] = s;
            }

            if (wvalid) {
                f32x4 v0 = {mv[0], mv[1], mv[2], mv[3]};
                f32x4 v1 = {mv[4], mv[5], mv[6], mv[7]};
                *(f32x4*)(a.m_s + (size_t)pos*32 + wave*8)     = v0;
                *(f32x4*)(a.m_s + (size_t)pos*32 + wave*8 + 4) = v1;
            }

            __syncthreads();
            float* mvx = smem;                     // 32 x 65 floats (overlays wk)
            #pragma unroll
            for (int ii = 0; ii < 8; ++ii)
                mvx[(wave*8 + ii)*65 + lane] = mv[ii];
            __syncthreads();
            if (wave == 0) {
                float m2[32];
                #pragma unroll
                for (int i = 0; i < 32; ++i) m2[i] = mvx[i*65 + lane];
                float phi = 0.f;
                for (int o = 0; o < 32; o += 4) {
                    f32x4 av = *(const f32x4*)(a.cmb1 + o);
                    #pragma unroll
                    for (int i = 0; i < 32; ++i)
                        av += m2[i] * (*(const f32x4*)(a.cmw1 + i*32 + o));
                    av = relu4(av);
                    f32x4 w2 = *(const f32x4*)(a.cmw2 + o);
                    phi += av.x*w2.x + av.y*w2.y + av.z*w2.z + av.w*w2.w;
                }
                if (wvalid) a.phis[pos] = phi;
            }
        }
        gg.sync();

        // ======== gather phase (+ fused final MLP on d==2) ========
        const int dofinal = (d == 2);
        if (gtid0 == 0) *a.tctr = 0;               // reset for next layer
        for (int tt = gtid0; tt < NN * 8; tt += gstride) {
            int n = tt >> 3, sub = tt & 7;
            int st = a.rowptr[n], en = a.rowptr[n+1];
            f32x4 am0 = {0.f, 0.f, 0.f, 0.f}, am1 = {0.f, 0.f, 0.f, 0.f};
            int p = st;
            for (; p + 1 < en; p += 2) {
                am0 += *(const f32x4*)(a.m_s + (size_t)p*32 + sub*4);
                am1 += *(const f32x4*)(a.m_s + (size_t)(p+1)*32 + sub*4);
            }
            if (p < en) am0 += *(const f32x4*)(a.m_s + (size_t)p*32 + sub*4);
            f32x4 am = am0 + am1;

            float di = a.deg_inv[n];
            f32x4 hv = *(const f32x4*)(a.h + (size_t)n*32 + sub*4);
            hv = relu4(hv + am * di);

            float c0 = 0.f, c1 = 0.f, c2 = 0.f;
            if (sub == 0) {
                float cx0 = 0.f, cy0 = 0.f, cz0 = 0.f;
                float cx1 = 0.f, cy1 = 0.f, cz1 = 0.f;
                int pp = st;
                for (; pp + 1 < en; pp += 2) {
                    f32x4 cd0 = *(const f32x4*)(a.cds + (size_t)pp*4);
                    f32x4 cd1 = *(const f32x4*)(a.cds + (size_t)(pp+1)*4);
                    float p0 = a.phis[pp], p1 = a.phis[pp+1];
                    cx0 += cd0.x * p0; cy0 += cd0.y * p0; cz0 += cd0.z * p0;
                    cx1 += cd1.x * p1; cy1 += cd1.y * p1; cz1 += cd1.z * p1;
                }
                if (pp < en) {
                    f32x4 cd0 = *(const f32x4*)(a.cds + (size_t)pp*4);
                    float p0 = a.phis[pp];
                    cx0 += cd0.x * p0; cy0 += cd0.y * p0; cz0 += cd0.z * p0;
                }
                c0 = a.coord[n*3+0] + (cx0 + cx1) * di;
                c1 = a.coord[n*3+1] + (cy0 + cy1) * di;
                c2 = a.coord[n*3+2] + (cz0 + cz1) * di;
            }

            if (!dofinal) {
                *(f32x4*)(a.h + (size_t)n*32 + sub*4) = hv;
                if (sub == 0) {
                    a.coord[n*3+0] = c0; a.coord[n*3+1] = c1; a.coord[n*3+2] = c2;
                }
            } else {
                // fused final MLP: collect h[0..31] via intra-group shfl
                const int gbase = (tid & 63) & 56;
                float hreg[32];
                #pragma unroll
                for (int s2 = 0; s2 < 8; ++s2) {
                    hreg[s2*4+0] = __shfl(hv.x, gbase + s2, 64);
                    hreg[s2*4+1] = __shfl(hv.y, gbase + s2, 64);
                    hreg[s2*4+2] = __shfl(hv.z, gbase + s2, 64);
                    hreg[s2*4+3] = __shfl(hv.w, gbase + s2, 64);
                }
                float po = 0.f;
                #pragma unroll
                for (int oo = 0; oo < 8; oo += 4) {
                    int o = sub*8 + oo;
                    f32x4 av = *(const f32x4*)(a.f2b1 + o);
                    #pragma unroll
                    for (int i = 0; i < 32; ++i)
                        av += hreg[i] * (*(const f32x4*)(a.f2w1 + i*64 + o));
                    av = relu4(av);
                    f32x4 w2 = *(const f32x4*)(a.f2w2 + o);
                    po += av.x*w2.x + av.y*w2.y + av.z*w2.z + av.w*w2.w;
                }
                po += __shfl_xor(po, 1, 64);
                po += __shfl_xor(po, 2, 64);
                po += __shfl_xor(po, 4, 64);
                if (sub == 0) {
                    a.out[n] = po + a.f2b2[0];
                    a.out[NN + n*3 + 0] = c0;
                    a.out[NN + n*3 + 1] = c1;
                    a.out[NN + n*3 + 2] = c2;
                }
            }
        }
        gg.sync();
    }
}

// ---------------- launch ----------------

extern "C" void kernel_launch(void* const* d_in, const int* in_sizes, int n_in,
                              void* d_out, int out_size, void* d_ws, size_t ws_size,
                              hipStream_t stream) {
    char* p = (char*)d_ws;
    auto carve = [&](size_t bytes) {
        void* r = (void*)p;
        p += (bytes + 255) & ~(size_t)255;
        return r;
    };
    MegaArgs a;
    a.x     = (const float*)d_in[0];
    a.eidx  = (const int*)  d_in[1];
    a.eattr = (const float*)d_in[2];
    a.cinit = (const float*)d_in[3];
    a.fc1w  = (const float*)d_in[4];
    a.fc1b  = (const float*)d_in[5];
    a.kw1   = (const float*)d_in[6];
    a.kb1   = (const float*)d_in[7];
    a.kw2   = (const float*)d_in[8];
    a.kb2   = (const float*)d_in[9];
    a.kw3   = (const float*)d_in[10];
    a.kb3   = (const float*)d_in[11];
    a.cmw1  = (const float*)d_in[12];
    a.cmb1  = (const float*)d_in[13];
    a.cmw2  = (const float*)d_in[14];
    a.f2w1  = (const float*)d_in[15];
    a.f2b1  = (const float*)d_in[16];
    a.f2w2  = (const float*)d_in[17];
    a.f2b2  = (const float*)d_in[18];
    a.out   = (float*)d_out;

    a.h       = (float*) carve((size_t)NN * 32 * 4);
    a.coord   = (float*) carve((size_t)NN * 3 * 4);
    a.deg     = (int*)   carve((size_t)NN * 4);
    a.deg_inv = (float*) carve((size_t)NN * 4);
    a.rowptr  = (int*)   carve((size_t)(NN + 1) * 4);
    a.cursor  = (int*)   carve((size_t)NN * 4);
    a.pos_r   = (int*)   carve((size_t)NE * 4);
    a.cds     = (float*) carve((size_t)NE * 4 * 4);
    a.m_s     = (float*) carve((size_t)NE * 32 * 4);
    a.phis    = (float*) carve((size_t)NE * 4);
    a.w3sw    = (__bf16*)carve((size_t)131072 * 2);
    a.w2sw    = (__bf16*)carve((size_t)8192 * 2);
    a.tctr    = (int*)   carve(256);

    // co-resident grid sizing (queries are deterministic & graph-safe)
    int maxb = 0;
    if (hipOccupancyMaxActiveBlocksPerMultiprocessor(&maxb, k_mega, 256, 0) != hipSuccess || maxb < 1)
        maxb = 1;
    int ncu = 256;
    int dev = 0;
    hipGetDevice(&dev);
    if (hipDeviceGetAttribute(&ncu, hipDeviceAttributeMultiprocessorCount, dev) != hipSuccess || ncu < 1)
        ncu = 256;
    int grid = maxb * ncu;
    if (grid > NTILES) grid = NTILES;

    void* kargs[] = { (void*)&a };
    hipLaunchCooperativeKernel((void*)k_mega, dim3(grid), dim3(256), kargs, 0, stream);
}

// Round 15
// 342.477 us; speedup vs baseline: 4.7797x; 4.7797x over previous
//
#include <hip/hip_runtime.h>
#include <hip/hip_bf16.h>

#define NN 10000
#define NE 100000

typedef __bf16 bf16x8 __attribute__((ext_vector_type(8)));
typedef float  f32x4  __attribute__((ext_vector_type(4)));
typedef unsigned int u32x4 __attribute__((ext_vector_type(4)));

__device__ __forceinline__ f32x4 relu4(f32x4 a) {
    a.x = fmaxf(a.x, 0.f); a.y = fmaxf(a.y, 0.f);
    a.z = fmaxf(a.z, 0.f); a.w = fmaxf(a.w, 0.f);
    return a;
}

// ---------------- one-time kernels ----------------

// Merged: w3/w2 swizzles + h/coord init + degree count (range-split grid).
// deg must be zeroed (memset) before this runs.
__global__ void k_setup(const float* __restrict__ w3, __bf16* __restrict__ w3sw,
                        const float* __restrict__ w2, __bf16* __restrict__ w2sw,
                        const float* __restrict__ x, const float* __restrict__ fc1w,
                        const float* __restrict__ fc1b, const float* __restrict__ cinit,
                        float* __restrict__ h, float* __restrict__ coord,
                        const int* __restrict__ eidx, int* __restrict__ deg) {
    int t = blockIdx.x * blockDim.x + threadIdx.x;
    if (t < 131072) {
        int jj = t & 7;
        int L  = (t >> 3) & 63;
        int ks = (t >> 9) & 3;
        int jt = (t >> 11) & 1;
        int i  = t >> 12;
        int c    = ks*32 + (L >> 4)*8 + jj;              // K index 0..127
        int colv = i*32 + jt*16 + (L & 15);              // output col 0..1023
        w3sw[t] = (__bf16)w3[c*1024 + colv];
    } else if (t < 139264) {
        int u = t - 131072;
        int jj = u & 7;
        int L  = (u >> 3) & 63;
        int ks = (u >> 9) & 1;
        int nt = u >> 10;
        int c1 = ks*32 + (L >> 4)*8 + jj;
        int c2 = nt*16 + (L & 15);
        w2sw[u] = (__bf16)w2[c1*128 + c2];
    } else if (t < 139264 + NN) {
        int n = t - 139264;
        float x0 = x[n*3+0], x1 = x[n*3+1], x2 = x[n*3+2];
        #pragma unroll
        for (int j = 0; j < 32; j += 4) {
            f32x4 a = *(const f32x4*)(fc1b + j);
            a += x0 * (*(const f32x4*)(fc1w + 0*32 + j));
            a += x1 * (*(const f32x4*)(fc1w + 1*32 + j));
            a += x2 * (*(const f32x4*)(fc1w + 2*32 + j));
            *(f32x4*)(h + n*32 + j) = a;   // no relu on fc1 (matches reference)
        }
        coord[n*3+0] = cinit[n*3+0];
        coord[n*3+1] = cinit[n*3+1];
        coord[n*3+2] = cinit[n*3+2];
    } else if (t < 139264 + NN + NE) {
        int e = t - 139264 - NN;
        atomicAdd(&deg[eidx[e]], 1);
    }
}

// Exclusive scan + deg_inv. One block of 1024 threads (CH=10).
__global__ __launch_bounds__(1024, 1)
void k_scan(const int* __restrict__ deg, int* __restrict__ rowptr,
            int* __restrict__ cursor, float* __restrict__ deg_inv) {
    __shared__ int ssum[1024];
    const int tid = threadIdx.x;
    const int CH = 10;                       // 1024*10 >= 10000
    const int base = tid * CH;
    int s = 0;
    for (int i = 0; i < CH; ++i) { int n = base + i; if (n < NN) s += deg[n]; }
    ssum[tid] = s;
    __syncthreads();
    for (int off = 1; off < 1024; off <<= 1) {
        int t = (tid >= off) ? ssum[tid - off] : 0;
        __syncthreads();
        ssum[tid] += t;
        __syncthreads();
    }
    int run = ssum[tid] - s;
    for (int i = 0; i < CH; ++i) {
        int n = base + i;
        if (n < NN) {
            int d = deg[n];
            rowptr[n] = run; cursor[n] = run; run += d;
            deg_inv[n] = 1.0f / (float)(d > 1 ? d : 1);
        }
    }
    if (tid == 1023) rowptr[NN] = ssum[1023];
}

__global__ void k_fill(const int* __restrict__ eidx, int* __restrict__ cursor,
                       int* __restrict__ pos_r) {
    int e = blockIdx.x * blockDim.x + threadIdx.x;
    if (e < NE) {
        int r = eidx[e];
        pos_r[e] = atomicAdd(&cursor[r], 1);
    }
}

// ---------------- the fused per-layer kernel ----------------
// LDS layout (36.9 KB): [wk: 4 waves x 64 rows x 20 u32 = 20480 B | kt2: 16384 B]
// kt1 (9216 B) overlays the wk region (dead before phase 3). wk holds bf16-packed
// col pairs (t, t+16) with a group-of-4 XOR bank swizzle -> <=2-way conflicts.
// Because wk no longer overlaps kt2, the post-afrag barrier is removed (4 barriers).
__global__ __launch_bounds__(256, 2)
void k_layer(const float* __restrict__ coord, const int* __restrict__ eidx,
             const float* __restrict__ eattr,
             const float* __restrict__ w1, const float* __restrict__ b1,
             const __bf16* __restrict__ w2sw, const float* __restrict__ b2,
             const __bf16* __restrict__ w3sw, const float* __restrict__ b3,
             const float* __restrict__ h,
             const float* __restrict__ cm_w1, const float* __restrict__ cm_b1,
             const float* __restrict__ cm_w2, const int* __restrict__ pos_r,
             float* __restrict__ cds, float* __restrict__ m_s,
             float* __restrict__ phis) {
    __shared__ unsigned smem_u[9216];              // 36864 B
    __bf16* kt1 = (__bf16*)smem_u;                 // 64 x 72 bf16 (overlays wk)
    __bf16* kt2 = (__bf16*)smem_u + 10240;         // [20480, 36864) B: 64 x 128 bf16
    const int lane = threadIdx.x & 63;
    const int wave = threadIdx.x >> 6;
    const int q = lane >> 4, t = lane & 15;
    const int base = blockIdx.x * 64;

    const int eg = base + lane;
    const int egc = eg < NE ? eg : NE - 1;
    const bool wvalid = eg < NE;
    const int pos = pos_r[egc];

    // early: gather h[col] + first B-frags (latency hidden by phases 1-2)
    int col = eidx[NE + egc];
    float hcol[32];
    {
        const f32x4* hp = (const f32x4*)(h + (size_t)col * 32);
        #pragma unroll
        for (int v = 0; v < 8; ++v) {
            f32x4 hv = hp[v];
            hcol[v*4+0] = hv.x; hcol[v*4+1] = hv.y; hcol[v*4+2] = hv.z; hcol[v*4+3] = hv.w;
        }
    }
    bf16x8 bcur[8];
    {
        const __bf16* wb0 = w3sw + (size_t)(wave * 8) * 4096;
        #pragma unroll
        for (int f = 0; f < 8; ++f)
            bcur[f] = *(const bf16x8*)(wb0 + (f*64 + lane) * 8);
    }

    // ---- phase 1: layer1, wave-split channels ----
    {
        int r = eidx[egc];
        float dx = coord[r*3+0] - coord[col*3+0];
        float dy = coord[r*3+1] - coord[col*3+1];
        float dz = coord[r*3+2] - coord[col*3+2];
        float rad = dx*dx + dy*dy + dz*dz;
        if (wave == 0 && wvalid) {
            f32x4 cdv = {dx, dy, dz, rad};
            *(f32x4*)(cds + (size_t)pos*4) = cdv;
        }
        float kin[7];
        #pragma unroll
        for (int a = 0; a < 6; ++a) kin[a] = eattr[(size_t)egc*6 + a];
        kin[6] = rad;

        const int g0 = wave * 16;
        f32x4 acc1[4];
        #pragma unroll
        for (int g = 0; g < 4; ++g) acc1[g] = *(const f32x4*)(b1 + g0 + g*4);
        #pragma unroll
        for (int t7 = 0; t7 < 7; ++t7) {
            float kv = kin[t7];
            #pragma unroll
            for (int g = 0; g < 4; ++g)
                acc1[g] += kv * (*(const f32x4*)(w1 + t7*64 + g0 + g*4));
        }
        #pragma unroll
        for (int cc = 0; cc < 2; ++cc) {
            f32x4 a0 = relu4(acc1[cc*2]), a1 = relu4(acc1[cc*2+1]);
            bf16x8 pk = {(__bf16)a0.x, (__bf16)a0.y, (__bf16)a0.z, (__bf16)a0.w,
                         (__bf16)a1.x, (__bf16)a1.y, (__bf16)a1.z, (__bf16)a1.w};
            int chunk = wave*2 + cc;
            *(bf16x8*)(kt1 + lane*72 + ((chunk ^ (lane & 7)) * 8)) = pk;
        }
    }
    __syncthreads();                               // k1 complete

    // ---- phase 2: layer2 MFMA (wave handles nt = 2*wave, 2*wave+1) ----
    {
        bf16x8 af[4][2];
        #pragma unroll
        for (int mt = 0; mt < 4; ++mt) {
            int ep = mt*16 + t;
            #pragma unroll
            for (int ks = 0; ks < 2; ++ks)
                af[mt][ks] = *(const bf16x8*)(kt1 + ep*72 + (((ks*4 + q) ^ (ep & 7)) * 8));
        }
        #pragma unroll
        for (int nn = 0; nn < 2; ++nn) {
            int nt = wave*2 + nn;
            f32x4 a2[4];
            #pragma unroll
            for (int mt = 0; mt < 4; ++mt) a2[mt] = (f32x4){0.f, 0.f, 0.f, 0.f};
            #pragma unroll
            for (int ks = 0; ks < 2; ++ks) {
                bf16x8 bf_ = *(const bf16x8*)(w2sw + ((nt*2 + ks)*64 + lane) * 8);
                #pragma unroll
                for (int mt = 0; mt < 4; ++mt)
                    a2[mt] = __builtin_amdgcn_mfma_f32_16x16x32_bf16(af[mt][ks], bf_, a2[mt], 0, 0, 0);
            }
            float bias = b2[nt*16 + t];
            int chunk = nt*2 + (t >> 3);
            int tin = t & 7;
            #pragma unroll
            for (int mt = 0; mt < 4; ++mt) {
                #pragma unroll
                for (int rr = 0; rr < 4; ++rr) {
                    int row = mt*16 + q*4 + rr;
                    kt2[row*128 + ((chunk ^ (row & 15)) * 8) + tin] =
                        (__bf16)fmaxf(a2[mt][rr] + bias, 0.f);
                }
            }
        }
    }
    __syncthreads();                               // k2 complete

    // ---- main A-frags from k2 tile (no barrier after: wk doesn't touch kt2) ----
    bf16x8 afrag[4][4];
    #pragma unroll
    for (int mt = 0; mt < 4; ++mt) {
        int ep = mt*16 + t;
        #pragma unroll
        for (int ks = 0; ks < 4; ++ks) {
            int ck = ks*4 + q;
            afrag[mt][ks] = *(const bf16x8*)(kt2 + ep*128 + ((ck ^ (ep & 15)) * 8));
        }
    }

    // ---- phase 3: big GEMM i-loop with bf16-packed wk ----
    unsigned* wkw = smem_u + wave * 1280;          // 64 rows x 20 u32
    const unsigned* wkrow = wkw + lane * 20;
    const int maskr = (lane ^ (lane >> 3)) & 3;
    float mv[8];

    #pragma unroll
    for (int ii = 0; ii < 8; ++ii) {
        const int i = wave * 8 + ii;
        f32x4 acc[4][2];
        #pragma unroll
        for (int mt = 0; mt < 4; ++mt) {
            acc[mt][0] = (f32x4){0.f, 0.f, 0.f, 0.f};
            acc[mt][1] = (f32x4){0.f, 0.f, 0.f, 0.f};
        }
        #pragma unroll
        for (int jt = 0; jt < 2; ++jt) {
            #pragma unroll
            for (int ks = 0; ks < 4; ++ks) {
                bf16x8 bfrag = bcur[jt*4 + ks];
                #pragma unroll
                for (int mt = 0; mt < 4; ++mt)
                    acc[mt][jt] = __builtin_amdgcn_mfma_f32_16x16x32_bf16(
                        afrag[mt][ks], bfrag, acc[mt][jt], 0, 0, 0);
            }
        }
        if (ii < 7) {
            const __bf16* wbn = w3sw + (size_t)(i + 1) * 4096;
            #pragma unroll
            for (int f = 0; f < 8; ++f)
                bcur[f] = *(const bf16x8*)(wbn + (f*64 + lane) * 8);
        }
        float bias0 = b3[i*32 + t];
        float bias1 = b3[i*32 + 16 + t];
        // pack cols (t, t+16) as bf16x2 -> one u32 store per row (16 stores)
        #pragma unroll
        for (int mt = 0; mt < 4; ++mt) {
            #pragma unroll
            for (int r = 0; r < 4; ++r) {
                int row = mt*16 + q*4 + r;
                float a0 = acc[mt][0][r] + bias0;
                float a1 = acc[mt][1][r] + bias1;
                unsigned u0 = (unsigned)__builtin_bit_cast(unsigned short, (__bf16)a0);
                unsigned u1 = (unsigned)__builtin_bit_cast(unsigned short, (__bf16)a1);
                int msk = (row ^ (row >> 3)) & 3;
                wkw[row*20 + ((((t >> 2) ^ msk) << 2) | (t & 3))] = u0 | (u1 << 16);
            }
        }
        // dot: 4 b128 reads of this lane's own row (same-wave ordering, no barrier)
        float s = 0.f;
        #pragma unroll
        for (int j = 0; j < 4; ++j) {
            u32x4 wv = *(const u32x4*)(wkrow + ((j ^ maskr) << 2));
            #pragma unroll
            for (int k = 0; k < 4; ++k) {
                unsigned w = wv[k];
                int c = j*4 + k;
                float flo = __uint_as_float(w << 16);
                float fhi = __uint_as_float(w & 0xFFFF0000u);
                s += flo * hcol[c] + fhi * hcol[16 + c];
            }
        }
        mv[ii] = s;
    }

    // store m at row-sorted slot
    if (wvalid) {
        f32x4 v0 = {mv[0], mv[1], mv[2], mv[3]};
        f32x4 v1 = {mv[4], mv[5], mv[6], mv[7]};
        *(f32x4*)(m_s + (size_t)pos*32 + wave*8)     = v0;
        *(f32x4*)(m_s + (size_t)pos*32 + wave*8 + 4) = v1;
    }

    __syncthreads();
    float* mvx = (float*)smem_u;                   // 32 x 65 floats (overlays wk)
    #pragma unroll
    for (int ii = 0; ii < 8; ++ii)
        mvx[(wave*8 + ii)*65 + lane] = mv[ii];
    __syncthreads();
    if (wave == 0) {
        float m2[32];
        #pragma unroll
        for (int i = 0; i < 32; ++i) m2[i] = mvx[i*65 + lane];
        float phi = 0.f;
        for (int o = 0; o < 32; o += 4) {
            f32x4 a = *(const f32x4*)(cm_b1 + o);
            #pragma unroll
            for (int i = 0; i < 32; ++i)
                a += m2[i] * (*(const f32x4*)(cm_w1 + i*32 + o));
            a = relu4(a);
            f32x4 w2 = *(const f32x4*)(cm_w2 + o);
            phi += a.x*w2.x + a.y*w2.y + a.z*w2.z + a.w*w2.w;
        }
        if (wvalid) phis[pos] = phi;
    }
}

// CSR gather over SORTED buffers (contiguous streams). 8 threads/node.
// dofinal: fuse the output MLP (h kept in regs, exchanged via intra-group shfl).
__global__ __launch_bounds__(256, 4)
void k_gather(const int* __restrict__ rowptr,
              const float* __restrict__ m_s, const float* __restrict__ phis,
              const float* __restrict__ cds, const float* __restrict__ deg_inv,
              float* __restrict__ coord, float* __restrict__ h,
              const float* __restrict__ fw1, const float* __restrict__ fb1,
              const float* __restrict__ fw2, const float* __restrict__ fb2,
              float* __restrict__ out, int dofinal) {
    int tid = blockIdx.x * blockDim.x + threadIdx.x;
    int n = tid >> 3, sub = tid & 7;
    if (n >= NN) return;
    int st = rowptr[n], en = rowptr[n+1];
    f32x4 am0 = {0.f, 0.f, 0.f, 0.f}, am1 = {0.f, 0.f, 0.f, 0.f};
    int p = st;
    for (; p + 1 < en; p += 2) {
        am0 += *(const f32x4*)(m_s + (size_t)p*32 + sub*4);
        am1 += *(const f32x4*)(m_s + (size_t)(p+1)*32 + sub*4);
    }
    if (p < en) am0 += *(const f32x4*)(m_s + (size_t)p*32 + sub*4);
    f32x4 am = am0 + am1;

    float di = deg_inv[n];
    f32x4 hv = *(const f32x4*)(h + (size_t)n*32 + sub*4);
    hv = relu4(hv + am * di);

    float c0 = 0.f, c1 = 0.f, c2 = 0.f;
    if (sub == 0) {
        float cx0 = 0.f, cy0 = 0.f, cz0 = 0.f;
        float cx1 = 0.f, cy1 = 0.f, cz1 = 0.f;
        int pp = st;
        for (; pp + 1 < en; pp += 2) {
            f32x4 cd0 = *(const f32x4*)(cds + (size_t)pp*4);
            f32x4 cd1 = *(const f32x4*)(cds + (size_t)(pp+1)*4);
            float p0 = phis[pp], p1 = phis[pp+1];
            cx0 += cd0.x * p0; cy0 += cd0.y * p0; cz0 += cd0.z * p0;
            cx1 += cd1.x * p1; cy1 += cd1.y * p1; cz1 += cd1.z * p1;
        }
        if (pp < en) {
            f32x4 cd0 = *(const f32x4*)(cds + (size_t)pp*4);
            float p0 = phis[pp];
            cx0 += cd0.x * p0; cy0 += cd0.y * p0; cz0 += cd0.z * p0;
        }
        c0 = coord[n*3+0] + (cx0 + cx1) * di;
        c1 = coord[n*3+1] + (cy0 + cy1) * di;
        c2 = coord[n*3+2] + (cz0 + cz1) * di;
    }

    if (!dofinal) {
        *(f32x4*)(h + (size_t)n*32 + sub*4) = hv;
        if (sub == 0) {
            coord[n*3+0] = c0; coord[n*3+1] = c1; coord[n*3+2] = c2;
        }
        return;
    }

    // fused final MLP: collect h[0..31] via intra-group shfl
    const int gbase = (tid & 63) & 56;
    float hreg[32];
    #pragma unroll
    for (int s2 = 0; s2 < 8; ++s2) {
        hreg[s2*4+0] = __shfl(hv.x, gbase + s2, 64);
        hreg[s2*4+1] = __shfl(hv.y, gbase + s2, 64);
        hreg[s2*4+2] = __shfl(hv.z, gbase + s2, 64);
        hreg[s2*4+3] = __shfl(hv.w, gbase + s2, 64);
    }
    float po = 0.f;
    #pragma unroll
    for (int oo = 0; oo < 8; oo += 4) {
        int o = sub*8 + oo;
        f32x4 a = *(const f32x4*)(fb1 + o);
        #pragma unroll
        for (int i = 0; i < 32; ++i)
            a += hreg[i] * (*(const f32x4*)(fw1 + i*64 + o));
        a = relu4(a);
        f32x4 w2 = *(const f32x4*)(fw2 + o);
        po += a.x*w2.x + a.y*w2.y + a.z*w2.z + a.w*w2.w;
    }
    po += __shfl_xor(po, 1, 64);
    po += __shfl_xor(po, 2, 64);
    po += __shfl_xor(po, 4, 64);
    if (sub == 0) {
        out[n] = po + fb2[0];
        out[NN + n*3 + 0] = c0;
        out[NN + n*3 + 1] = c1;
        out[NN + n*3 + 2] = c2;
    }
}

// ---------------- launch ----------------

extern "C" void kernel_launch(void* const* d_in, const int* in_sizes, int n_in,
                              void* d_out, int out_size, void* d_ws, size_t ws_size,
                              hipStream_t stream) {
    const float* x      = (const float*)d_in[0];
    const int*   eidx   = (const int*)  d_in[1];
    const float* eattr  = (const float*)d_in[2];
    const float* cinit  = (const float*)d_in[3];
    const float* fc1w   = (const float*)d_in[4];
    const float* fc1b   = (const float*)d_in[5];
    const float* kw1    = (const float*)d_in[6];
    const float* kb1    = (const float*)d_in[7];
    const float* kw2    = (const float*)d_in[8];
    const float* kb2    = (const float*)d_in[9];
    const float* kw3    = (const float*)d_in[10];
    const float* kb3    = (const float*)d_in[11];
    const float* cmw1   = (const float*)d_in[12];
    const float* cmb1   = (const float*)d_in[13];
    const float* cmw2   = (const float*)d_in[14];
    const float* f2w1   = (const float*)d_in[15];
    const float* f2b1   = (const float*)d_in[16];
    const float* f2w2   = (const float*)d_in[17];
    const float* f2b2   = (const float*)d_in[18];
    float* out = (float*)d_out;

    char* p = (char*)d_ws;
    auto carve = [&](size_t bytes) {
        void* r = (void*)p;
        p += (bytes + 255) & ~(size_t)255;
        return r;
    };
    float*  h        = (float*) carve((size_t)NN * 32 * 4);
    float*  coord    = (float*) carve((size_t)NN * 3 * 4);
    int*    deg      = (int*)   carve((size_t)NN * 4);
    float*  deg_inv  = (float*) carve((size_t)NN * 4);
    int*    rowptr   = (int*)   carve((size_t)(NN + 1) * 4);
    int*    cursor   = (int*)   carve((size_t)NN * 4);
    int*    pos_r    = (int*)   carve((size_t)NE * 4);
    float*  cds      = (float*) carve((size_t)NE * 4 * 4);
    float*  m_s      = (float*) carve((size_t)NE * 32 * 4);
    float*  phis     = (float*) carve((size_t)NE * 4);
    __bf16* w3sw     = (__bf16*)carve((size_t)131072 * 2);
    __bf16* w2sw     = (__bf16*)carve((size_t)8192 * 2);

    const int TB = 256;
    dim3 gE((NE + TB - 1) / TB), b(TB);
    dim3 gS((139264 + NN + NE + TB - 1) / TB);
    dim3 gG((NE + 63) / 64);
    dim3 gA((NN*8 + TB - 1) / TB);

    hipMemsetAsync(deg, 0, (size_t)NN * 4, stream);
    k_setup<<<gS, b, 0, stream>>>(kw3, w3sw, kw2, w2sw, x, fc1w, fc1b, cinit,
                                  h, coord, eidx, deg);
    k_scan <<<1, dim3(1024), 0, stream>>>(deg, rowptr, cursor, deg_inv);
    k_fill <<<gE, b, 0, stream>>>(eidx, cursor, pos_r);

    for (int d = 0; d < 3; ++d) {
        k_layer<<<gG, b, 0, stream>>>(coord, eidx, eattr, kw1, kb1, w2sw, kb2,
                                      w3sw, kb3, h, cmw1, cmb1, cmw2, pos_r,
                                      cds, m_s, phis);
        k_gather<<<gA, b, 0, stream>>>(rowptr, m_s, phis, cds, deg_inv, coord, h,
                                       f2w1, f2b1, f2w2, f2b2, out, d == 2 ? 1 : 0);
    }
}

// Round 16
// 332.213 us; speedup vs baseline: 4.9273x; 1.0309x over previous
//
#include <hip/hip_runtime.h>
#include <hip/hip_bf16.h>

#define NN 10000
#define NE 100000

typedef __bf16 bf16x8 __attribute__((ext_vector_type(8)));
typedef float  f32x4  __attribute__((ext_vector_type(4)));
typedef unsigned int u32x4 __attribute__((ext_vector_type(4)));

__device__ __forceinline__ f32x4 relu4(f32x4 a) {
    a.x = fmaxf(a.x, 0.f); a.y = fmaxf(a.y, 0.f);
    a.z = fmaxf(a.z, 0.f); a.w = fmaxf(a.w, 0.f);
    return a;
}

// ---------------- one-time kernels ----------------

// Merged: w3/w2 swizzles + h/coord init + degree count (range-split grid).
// The degree atomicAdd's return value IS the edge's within-node rank -> within[e].
// deg must be zeroed (memset) before this runs.
__global__ void k_setup(const float* __restrict__ w3, __bf16* __restrict__ w3sw,
                        const float* __restrict__ w2, __bf16* __restrict__ w2sw,
                        const float* __restrict__ x, const float* __restrict__ fc1w,
                        const float* __restrict__ fc1b, const float* __restrict__ cinit,
                        float* __restrict__ h, float* __restrict__ coord,
                        const int* __restrict__ eidx, int* __restrict__ deg,
                        int* __restrict__ within) {
    int t = blockIdx.x * blockDim.x + threadIdx.x;
    if (t < 131072) {
        int jj = t & 7;
        int L  = (t >> 3) & 63;
        int ks = (t >> 9) & 3;
        int jt = (t >> 11) & 1;
        int i  = t >> 12;
        int c    = ks*32 + (L >> 4)*8 + jj;              // K index 0..127
        int colv = i*32 + jt*16 + (L & 15);              // output col 0..1023
        w3sw[t] = (__bf16)w3[c*1024 + colv];
    } else if (t < 139264) {
        int u = t - 131072;
        int jj = u & 7;
        int L  = (u >> 3) & 63;
        int ks = (u >> 9) & 1;
        int nt = u >> 10;
        int c1 = ks*32 + (L >> 4)*8 + jj;
        int c2 = nt*16 + (L & 15);
        w2sw[u] = (__bf16)w2[c1*128 + c2];
    } else if (t < 139264 + NN) {
        int n = t - 139264;
        float x0 = x[n*3+0], x1 = x[n*3+1], x2 = x[n*3+2];
        #pragma unroll
        for (int j = 0; j < 32; j += 4) {
            f32x4 a = *(const f32x4*)(fc1b + j);
            a += x0 * (*(const f32x4*)(fc1w + 0*32 + j));
            a += x1 * (*(const f32x4*)(fc1w + 1*32 + j));
            a += x2 * (*(const f32x4*)(fc1w + 2*32 + j));
            *(f32x4*)(h + n*32 + j) = a;   // no relu on fc1 (matches reference)
        }
        coord[n*3+0] = cinit[n*3+0];
        coord[n*3+1] = cinit[n*3+1];
        coord[n*3+2] = cinit[n*3+2];
    } else if (t < 139264 + NN + NE) {
        int e = t - 139264 - NN;
        within[e] = atomicAdd(&deg[eidx[e]], 1);
    }
}

// Exclusive scan + deg_inv. One block of 1024 threads (CH=10).
__global__ __launch_bounds__(1024, 1)
void k_scan(const int* __restrict__ deg, int* __restrict__ rowptr,
            float* __restrict__ deg_inv) {
    __shared__ int ssum[1024];
    const int tid = threadIdx.x;
    const int CH = 10;                       // 1024*10 >= 10000
    const int base = tid * CH;
    int s = 0;
    for (int i = 0; i < CH; ++i) { int n = base + i; if (n < NN) s += deg[n]; }
    ssum[tid] = s;
    __syncthreads();
    for (int off = 1; off < 1024; off <<= 1) {
        int t = (tid >= off) ? ssum[tid - off] : 0;
        __syncthreads();
        ssum[tid] += t;
        __syncthreads();
    }
    int run = ssum[tid] - s;
    for (int i = 0; i < CH; ++i) {
        int n = base + i;
        if (n < NN) {
            int d = deg[n];
            rowptr[n] = run; run += d;
            deg_inv[n] = 1.0f / (float)(d > 1 ? d : 1);
        }
    }
    if (tid == 1023) rowptr[NN] = ssum[1023];
}

// ---------------- the fused per-layer kernel ----------------
// LDS = 26624 B total (was 36864): kt1 [0,9216), kt2 [10240,26624).
// wk (bf16-packed, 4 waves x 64 rows x 20 u32 = 20480 B) OVERLAYS [0,20480)
// -- legal because kt1/kt2 are dead after the afrag loads; the post-afrag
// barrier (restored; round-13 measured it cheap) orders the overlay.
// Occupancy experiment: 26.0 KB -> up to 6 blocks/CU by LDS (4 by VGPR).
__global__ __launch_bounds__(256, 2)
void k_layer(const float* __restrict__ coord, const int* __restrict__ eidx,
             const float* __restrict__ eattr,
             const float* __restrict__ w1, const float* __restrict__ b1,
             const __bf16* __restrict__ w2sw, const float* __restrict__ b2,
             const __bf16* __restrict__ w3sw, const float* __restrict__ b3,
             const float* __restrict__ h,
             const float* __restrict__ cm_w1, const float* __restrict__ cm_b1,
             const float* __restrict__ cm_w2,
             const int* __restrict__ rowptr, const int* __restrict__ within,
             float* __restrict__ cds, float* __restrict__ m_s,
             float* __restrict__ phis) {
    __shared__ unsigned smem_u[6656];              // 26624 B
    __bf16* kt1 = (__bf16*)smem_u;                 // [0, 9216) B : 64 x 72 bf16
    __bf16* kt2 = (__bf16*)smem_u + 5120;          // [10240, 26624) B : 64 x 128 bf16
    const int lane = threadIdx.x & 63;
    const int wave = threadIdx.x >> 6;
    const int q = lane >> 4, t = lane & 15;
    const int base = blockIdx.x * 64;

    const int eg = base + lane;
    const int egc = eg < NE ? eg : NE - 1;
    const bool wvalid = eg < NE;
    const int r_node = eidx[egc];
    const int pos = rowptr[r_node] + within[egc];

    // early: gather h[col] + first B-frags (latency hidden by phases 1-2)
    int col = eidx[NE + egc];
    float hcol[32];
    {
        const f32x4* hp = (const f32x4*)(h + (size_t)col * 32);
        #pragma unroll
        for (int v = 0; v < 8; ++v) {
            f32x4 hv = hp[v];
            hcol[v*4+0] = hv.x; hcol[v*4+1] = hv.y; hcol[v*4+2] = hv.z; hcol[v*4+3] = hv.w;
        }
    }
    bf16x8 bcur[8];
    {
        const __bf16* wb0 = w3sw + (size_t)(wave * 8) * 4096;
        #pragma unroll
        for (int f = 0; f < 8; ++f)
            bcur[f] = *(const bf16x8*)(wb0 + (f*64 + lane) * 8);
    }

    // ---- phase 1: layer1, wave-split channels ----
    {
        float dx = coord[r_node*3+0] - coord[col*3+0];
        float dy = coord[r_node*3+1] - coord[col*3+1];
        float dz = coord[r_node*3+2] - coord[col*3+2];
        float rad = dx*dx + dy*dy + dz*dz;
        if (wave == 0 && wvalid) {
            f32x4 cdv = {dx, dy, dz, rad};
            *(f32x4*)(cds + (size_t)pos*4) = cdv;
        }
        float kin[7];
        #pragma unroll
        for (int a = 0; a < 6; ++a) kin[a] = eattr[(size_t)egc*6 + a];
        kin[6] = rad;

        const int g0 = wave * 16;
        f32x4 acc1[4];
        #pragma unroll
        for (int g = 0; g < 4; ++g) acc1[g] = *(const f32x4*)(b1 + g0 + g*4);
        #pragma unroll
        for (int t7 = 0; t7 < 7; ++t7) {
            float kv = kin[t7];
            #pragma unroll
            for (int g = 0; g < 4; ++g)
                acc1[g] += kv * (*(const f32x4*)(w1 + t7*64 + g0 + g*4));
        }
        #pragma unroll
        for (int cc = 0; cc < 2; ++cc) {
            f32x4 a0 = relu4(acc1[cc*2]), a1 = relu4(acc1[cc*2+1]);
            bf16x8 pk = {(__bf16)a0.x, (__bf16)a0.y, (__bf16)a0.z, (__bf16)a0.w,
                         (__bf16)a1.x, (__bf16)a1.y, (__bf16)a1.z, (__bf16)a1.w};
            int chunk = wave*2 + cc;
            *(bf16x8*)(kt1 + lane*72 + ((chunk ^ (lane & 7)) * 8)) = pk;
        }
    }
    __syncthreads();                               // k1 complete

    // ---- phase 2: layer2 MFMA (wave handles nt = 2*wave, 2*wave+1) ----
    {
        bf16x8 af[4][2];
        #pragma unroll
        for (int mt = 0; mt < 4; ++mt) {
            int ep = mt*16 + t;
            #pragma unroll
            for (int ks = 0; ks < 2; ++ks)
                af[mt][ks] = *(const bf16x8*)(kt1 + ep*72 + (((ks*4 + q) ^ (ep & 7)) * 8));
        }
        #pragma unroll
        for (int nn = 0; nn < 2; ++nn) {
            int nt = wave*2 + nn;
            f32x4 a2[4];
            #pragma unroll
            for (int mt = 0; mt < 4; ++mt) a2[mt] = (f32x4){0.f, 0.f, 0.f, 0.f};
            #pragma unroll
            for (int ks = 0; ks < 2; ++ks) {
                bf16x8 bf_ = *(const bf16x8*)(w2sw + ((nt*2 + ks)*64 + lane) * 8);
                #pragma unroll
                for (int mt = 0; mt < 4; ++mt)
                    a2[mt] = __builtin_amdgcn_mfma_f32_16x16x32_bf16(af[mt][ks], bf_, a2[mt], 0, 0, 0);
            }
            float bias = b2[nt*16 + t];
            int chunk = nt*2 + (t >> 3);
            int tin = t & 7;
            #pragma unroll
            for (int mt = 0; mt < 4; ++mt) {
                #pragma unroll
                for (int rr = 0; rr < 4; ++rr) {
                    int row = mt*16 + q*4 + rr;
                    kt2[row*128 + ((chunk ^ (row & 15)) * 8) + tin] =
                        (__bf16)fmaxf(a2[mt][rr] + bias, 0.f);
                }
            }
        }
    }
    __syncthreads();                               // k2 complete

    // ---- main A-frags from k2 tile ----
    bf16x8 afrag[4][4];
    #pragma unroll
    for (int mt = 0; mt < 4; ++mt) {
        int ep = mt*16 + t;
        #pragma unroll
        for (int ks = 0; ks < 4; ++ks) {
            int ck = ks*4 + q;
            afrag[mt][ks] = *(const bf16x8*)(kt2 + ep*128 + ((ck ^ (ep & 15)) * 8));
        }
    }
    __syncthreads();                               // afrag loaded; wk overlays kt1/kt2

    // ---- phase 3: big GEMM i-loop with bf16-packed wk ----
    unsigned* wkw = smem_u + wave * 1280;          // 64 rows x 20 u32
    const unsigned* wkrow = wkw + lane * 20;
    const int maskr = (lane ^ (lane >> 3)) & 3;
    float mv[8];

    #pragma unroll
    for (int ii = 0; ii < 8; ++ii) {
        const int i = wave * 8 + ii;
        f32x4 acc[4][2];
        #pragma unroll
        for (int mt = 0; mt < 4; ++mt) {
            acc[mt][0] = (f32x4){0.f, 0.f, 0.f, 0.f};
            acc[mt][1] = (f32x4){0.f, 0.f, 0.f, 0.f};
        }
        #pragma unroll
        for (int jt = 0; jt < 2; ++jt) {
            #pragma unroll
            for (int ks = 0; ks < 4; ++ks) {
                bf16x8 bfrag = bcur[jt*4 + ks];
                #pragma unroll
                for (int mt = 0; mt < 4; ++mt)
                    acc[mt][jt] = __builtin_amdgcn_mfma_f32_16x16x32_bf16(
                        afrag[mt][ks], bfrag, acc[mt][jt], 0, 0, 0);
            }
        }
        if (ii < 7) {
            const __bf16* wbn = w3sw + (size_t)(i + 1) * 4096;
            #pragma unroll
            for (int f = 0; f < 8; ++f)
                bcur[f] = *(const bf16x8*)(wbn + (f*64 + lane) * 8);
        }
        float bias0 = b3[i*32 + t];
        float bias1 = b3[i*32 + 16 + t];
        // pack cols (t, t+16) as bf16x2 -> one u32 store per row (16 stores)
        #pragma unroll
        for (int mt = 0; mt < 4; ++mt) {
            #pragma unroll
            for (int r = 0; r < 4; ++r) {
                int row = mt*16 + q*4 + r;
                float a0 = acc[mt][0][r] + bias0;
                float a1 = acc[mt][1][r] + bias1;
                unsigned u0 = (unsigned)__builtin_bit_cast(unsigned short, (__bf16)a0);
                unsigned u1 = (unsigned)__builtin_bit_cast(unsigned short, (__bf16)a1);
                int msk = (row ^ (row >> 3)) & 3;
                wkw[row*20 + ((((t >> 2) ^ msk) << 2) | (t & 3))] = u0 | (u1 << 16);
            }
        }
        // dot: 4 b128 reads of this lane's own row (same-wave ordering, no barrier)
        float s = 0.f;
        #pragma unroll
        for (int j = 0; j < 4; ++j) {
            u32x4 wv = *(const u32x4*)(wkrow + ((j ^ maskr) << 2));
            #pragma unroll
            for (int k = 0; k < 4; ++k) {
                unsigned w = wv[k];
                int c = j*4 + k;
                float flo = __uint_as_float(w << 16);
                float fhi = __uint_as_float(w & 0xFFFF0000u);
                s += flo * hcol[c] + fhi * hcol[16 + c];
            }
        }
        mv[ii] = s;
    }

    // store m at row-sorted slot
    if (wvalid) {
        f32x4 v0 = {mv[0], mv[1], mv[2], mv[3]};
        f32x4 v1 = {mv[4], mv[5], mv[6], mv[7]};
        *(f32x4*)(m_s + (size_t)pos*32 + wave*8)     = v0;
        *(f32x4*)(m_s + (size_t)pos*32 + wave*8 + 4) = v1;
    }

    __syncthreads();
    float* mvx = (float*)smem_u;                   // 32 x 65 floats (overlays wk)
    #pragma unroll
    for (int ii = 0; ii < 8; ++ii)
        mvx[(wave*8 + ii)*65 + lane] = mv[ii];
    __syncthreads();
    if (wave == 0) {
        float m2[32];
        #pragma unroll
        for (int i = 0; i < 32; ++i) m2[i] = mvx[i*65 + lane];
        float phi = 0.f;
        for (int o = 0; o < 32; o += 4) {
            f32x4 a = *(const f32x4*)(cm_b1 + o);
            #pragma unroll
            for (int i = 0; i < 32; ++i)
                a += m2[i] * (*(const f32x4*)(cm_w1 + i*32 + o));
            a = relu4(a);
            f32x4 w2 = *(const f32x4*)(cm_w2 + o);
            phi += a.x*w2.x + a.y*w2.y + a.z*w2.z + a.w*w2.w;
        }
        if (wvalid) phis[pos] = phi;
    }
}

// CSR gather over SORTED buffers (contiguous streams). 8 threads/node.
// dofinal: fuse the output MLP (h kept in regs, exchanged via intra-group shfl).
__global__ __launch_bounds__(256, 4)
void k_gather(const int* __restrict__ rowptr,
              const float* __restrict__ m_s, const float* __restrict__ phis,
              const float* __restrict__ cds, const float* __restrict__ deg_inv,
              float* __restrict__ coord, float* __restrict__ h,
              const float* __restrict__ fw1, const float* __restrict__ fb1,
              const float* __restrict__ fw2, const float* __restrict__ fb2,
              float* __restrict__ out, int dofinal) {
    int tid = blockIdx.x * blockDim.x + threadIdx.x;
    int n = tid >> 3, sub = tid & 7;
    if (n >= NN) return;
    int st = rowptr[n], en = rowptr[n+1];
    f32x4 am0 = {0.f, 0.f, 0.f, 0.f}, am1 = {0.f, 0.f, 0.f, 0.f};
    int p = st;
    for (; p + 1 < en; p += 2) {
        am0 += *(const f32x4*)(m_s + (size_t)p*32 + sub*4);
        am1 += *(const f32x4*)(m_s + (size_t)(p+1)*32 + sub*4);
    }
    if (p < en) am0 += *(const f32x4*)(m_s + (size_t)p*32 + sub*4);
    f32x4 am = am0 + am1;

    float di = deg_inv[n];
    f32x4 hv = *(const f32x4*)(h + (size_t)n*32 + sub*4);
    hv = relu4(hv + am * di);

    float c0 = 0.f, c1 = 0.f, c2 = 0.f;
    if (sub == 0) {
        float cx0 = 0.f, cy0 = 0.f, cz0 = 0.f;
        float cx1 = 0.f, cy1 = 0.f, cz1 = 0.f;
        int pp = st;
        for (; pp + 1 < en; pp += 2) {
            f32x4 cd0 = *(const f32x4*)(cds + (size_t)pp*4);
            f32x4 cd1 = *(const f32x4*)(cds + (size_t)(pp+1)*4);
            float p0 = phis[pp], p1 = phis[pp+1];
            cx0 += cd0.x * p0; cy0 += cd0.y * p0; cz0 += cd0.z * p0;
            cx1 += cd1.x * p1; cy1 += cd1.y * p1; cz1 += cd1.z * p1;
        }
        if (pp < en) {
            f32x4 cd0 = *(const f32x4*)(cds + (size_t)pp*4);
            float p0 = phis[pp];
            cx0 += cd0.x * p0; cy0 += cd0.y * p0; cz0 += cd0.z * p0;
        }
        c0 = coord[n*3+0] + (cx0 + cx1) * di;
        c1 = coord[n*3+1] + (cy0 + cy1) * di;
        c2 = coord[n*3+2] + (cz0 + cz1) * di;
    }

    if (!dofinal) {
        *(f32x4*)(h + (size_t)n*32 + sub*4) = hv;
        if (sub == 0) {
            coord[n*3+0] = c0; coord[n*3+1] = c1; coord[n*3+2] = c2;
        }
        return;
    }

    // fused final MLP: collect h[0..31] via intra-group shfl
    const int gbase = (tid & 63) & 56;
    float hreg[32];
    #pragma unroll
    for (int s2 = 0; s2 < 8; ++s2) {
        hreg[s2*4+0] = __shfl(hv.x, gbase + s2, 64);
        hreg[s2*4+1] = __shfl(hv.y, gbase + s2, 64);
        hreg[s2*4+2] = __shfl(hv.z, gbase + s2, 64);
        hreg[s2*4+3] = __shfl(hv.w, gbase + s2, 64);
    }
    float po = 0.f;
    #pragma unroll
    for (int oo = 0; oo < 8; oo += 4) {
        int o = sub*8 + oo;
        f32x4 a = *(const f32x4*)(fb1 + o);
        #pragma unroll
        for (int i = 0; i < 32; ++i)
            a += hreg[i] * (*(const f32x4*)(fw1 + i*64 + o));
        a = relu4(a);
        f32x4 w2 = *(const f32x4*)(fw2 + o);
        po += a.x*w2.x + a.y*w2.y + a.z*w2.z + a.w*w2.w;
    }
    po += __shfl_xor(po, 1, 64);
    po += __shfl_xor(po, 2, 64);
    po += __shfl_xor(po, 4, 64);
    if (sub == 0) {
        out[n] = po + fb2[0];
        out[NN + n*3 + 0] = c0;
        out[NN + n*3 + 1] = c1;
        out[NN + n*3 + 2] = c2;
    }
}

// ---------------- launch ----------------

extern "C" void kernel_launch(void* const* d_in, const int* in_sizes, int n_in,
                              void* d_out, int out_size, void* d_ws, size_t ws_size,
                              hipStream_t stream) {
    const float* x      = (const float*)d_in[0];
    const int*   eidx   = (const int*)  d_in[1];
    const float* eattr  = (const float*)d_in[2];
    const float* cinit  = (const float*)d_in[3];
    const float* fc1w   = (const float*)d_in[4];
    const float* fc1b   = (const float*)d_in[5];
    const float* kw1    = (const float*)d_in[6];
    const float* kb1    = (const float*)d_in[7];
    const float* kw2    = (const float*)d_in[8];
    const float* kb2    = (const float*)d_in[9];
    const float* kw3    = (const float*)d_in[10];
    const float* kb3    = (const float*)d_in[11];
    const float* cmw1   = (const float*)d_in[12];
    const float* cmb1   = (const float*)d_in[13];
    const float* cmw2   = (const float*)d_in[14];
    const float* f2w1   = (const float*)d_in[15];
    const float* f2b1   = (const float*)d_in[16];
    const float* f2w2   = (const float*)d_in[17];
    const float* f2b2   = (const float*)d_in[18];
    float* out = (float*)d_out;

    char* p = (char*)d_ws;
    auto carve = [&](size_t bytes) {
        void* r = (void*)p;
        p += (bytes + 255) & ~(size_t)255;
        return r;
    };
    float*  h        = (float*) carve((size_t)NN * 32 * 4);
    float*  coord    = (float*) carve((size_t)NN * 3 * 4);
    int*    deg      = (int*)   carve((size_t)NN * 4);
    float*  deg_inv  = (float*) carve((size_t)NN * 4);
    int*    rowptr   = (int*)   carve((size_t)(NN + 1) * 4);
    int*    within   = (int*)   carve((size_t)NE * 4);
    float*  cds      = (float*) carve((size_t)NE * 4 * 4);
    float*  m_s      = (float*) carve((size_t)NE * 32 * 4);
    float*  phis     = (float*) carve((size_t)NE * 4);
    __bf16* w3sw     = (__bf16*)carve((size_t)131072 * 2);
    __bf16* w2sw     = (__bf16*)carve((size_t)8192 * 2);

    const int TB = 256;
    dim3 b(TB);
    dim3 gS((139264 + NN + NE + TB - 1) / TB);
    dim3 gG((NE + 63) / 64);
    dim3 gA((NN*8 + TB - 1) / TB);

    hipMemsetAsync(deg, 0, (size_t)NN * 4, stream);
    k_setup<<<gS, b, 0, stream>>>(kw3, w3sw, kw2, w2sw, x, fc1w, fc1b, cinit,
                                  h, coord, eidx, deg, within);
    k_scan <<<1, dim3(1024), 0, stream>>>(deg, rowptr, deg_inv);

    for (int d = 0; d < 3; ++d) {
        k_layer<<<gG, b, 0, stream>>>(coord, eidx, eattr, kw1, kb1, w2sw, kb2,
                                      w3sw, kb3, h, cmw1, cmb1, cmw2,
                                      rowptr, within, cds, m_s, phis);
        k_gather<<<gA, b, 0, stream>>>(rowptr, m_s, phis, cds, deg_inv, coord, h,
                                       f2w1, f2b1, f2w2, f2b2, out, d == 2 ? 1 : 0);
    }
}